// Round 1
// baseline (298.232 us; speedup 1.0000x reference)
//
#include <hip/hip_runtime.h>
#include <stdint.h>

typedef __attribute__((ext_vector_type(8))) short short8;
typedef __attribute__((ext_vector_type(4))) float f32x4;
typedef unsigned short u16;
typedef unsigned int u32;

#define H_ 8
#define A_ 16
#define C_ 512
#define D_ 64
#define HW_ 4096
#define B_ 32
#define M_ (B_*HW_)   // 131072

__device__ __forceinline__ u16 f2b(float f){
  u32 u = __float_as_uint(f);
  u += 0x7FFFu + ((u >> 16) & 1u);
  return (u16)(u >> 16);
}
__device__ __forceinline__ float b2f(u16 h){ return __uint_as_float(((u32)h) << 16); }

// ---------------- prep kernels (tiny) ----------------
__global__ void prep_kv(const float* __restrict__ agent_k, const float* __restrict__ Wk, const float* __restrict__ bk,
                        const float* __restrict__ agent_v, const float* __restrict__ Wv, const float* __restrict__ bv,
                        float* __restrict__ k2, float* __restrict__ v2)
{
  int a = blockIdx.x, t = threadIdx.x;
  __shared__ float ak[C_], av[C_];
  for (int c = t; c < C_; c += 256){ ak[c] = agent_k[a*C_+c]; av[c] = agent_v[a*C_+c]; }
  __syncthreads();
  for (int c = t; c < C_; c += 256){
    float sk = bk[c], sv = bv[c];
    for (int cc = 0; cc < C_; ++cc){
      float wk = Wk[cc*C_+c], wv = Wv[cc*C_+c];
      sk += ak[cc]*wk; sv += av[cc]*wv;
    }
    k2[a*C_+c] = sk; v2[a*C_+c] = sv;
  }
}

// WqkT[ha][c] = scale * sum_d Wq[c][h*64+d] * k2[a][h*64+d]   (bf16)
// bqk[ha]    = scale * sum_d bq[h*64+d]    * k2[a][h*64+d]
__global__ void prep_wqk(const float* __restrict__ Wq, const float* __restrict__ bq,
                         const float* __restrict__ k2, u16* __restrict__ WqkT, float* __restrict__ bqk)
{
  int c = blockIdx.x, t = threadIdx.x; // t = ha in [0,128)
  int h = t >> 4, a = t & 15;
  float s = 0.f;
  for (int d = 0; d < D_; ++d) s += Wq[c*C_ + h*D_ + d] * k2[a*C_ + h*D_ + d];
  WqkT[t*C_ + c] = f2b(s * 0.125f);
  if (c == 0){
    float sb = 0.f;
    for (int d = 0; d < D_; ++d) sb += bq[h*D_ + d] * k2[a*C_ + h*D_ + d];
    bqk[t] = sb * 0.125f;
  }
}

// WvpT[co][ha] = sum_d v2[a][h*64+d] * Wp[(h*64+d)][co]   (bf16)
__global__ void prep_wvp(const float* __restrict__ Wp, const float* __restrict__ v2, u16* __restrict__ WvpT)
{
  int ha = blockIdx.x; int h = ha >> 4, a = ha & 15;
  __shared__ float vsh[D_];
  if (threadIdx.x < D_) vsh[threadIdx.x] = v2[a*C_ + h*D_ + threadIdx.x];
  __syncthreads();
  for (int co = threadIdx.x; co < C_; co += 256){
    float s = 0.f;
    for (int d = 0; d < D_; ++d) s += vsh[d] * Wp[(h*D_ + d)*C_ + co];
    WvpT[co*128 + ha] = f2b(s);
  }
}

// ---------------- pass A: scores GEMM + softmax + reductions ----------------
// grid 1024 blocks (128 rows each), 256 threads (4 waves). N=128, K=512.
__global__ __launch_bounds__(256) void pass_a(
    const float* __restrict__ x, const u16* __restrict__ WqkT,
    const float* __restrict__ bqk, u16* __restrict__ attn,
    float* __restrict__ gsum, u32* __restrict__ gmax)
{
  __shared__ u16 xs[128*64];
  __shared__ u16 bs[128*64];
  const int t = threadIdx.x;
  const int m0 = blockIdx.x * 128;
  const int b = blockIdx.x >> 5;
  const int w = t >> 6, lane = t & 63;
  const int la = lane & 15, rg = lane >> 4;
  const int swz = (la & 7) << 3;

  f32x4 acc[2][8];
  #pragma unroll
  for (int i = 0; i < 2; ++i)
    #pragma unroll
    for (int j = 0; j < 8; ++j) acc[i][j] = (f32x4){0.f,0.f,0.f,0.f};

  const int srow = t >> 2;          // 0..63
  const int scol = (t & 3) << 4;    // 0,16,32,48

  for (int kt = 0; kt < 8; ++kt) {
    const int k0 = kt * 64;
    __syncthreads();
    // stage x tile (fp32 -> bf16), rows srow & srow+64, 16 cols each
    #pragma unroll
    for (int rr = 0; rr < 2; ++rr) {
      const int row = srow + rr*64;
      const float* src = x + (size_t)(m0 + row)*C_ + k0 + scol;
      float4 f0 = ((const float4*)src)[0];
      float4 f1 = ((const float4*)src)[1];
      float4 f2 = ((const float4*)src)[2];
      float4 f3 = ((const float4*)src)[3];
      short8 p0, p1;
      p0[0]=(short)f2b(f0.x); p0[1]=(short)f2b(f0.y); p0[2]=(short)f2b(f0.z); p0[3]=(short)f2b(f0.w);
      p0[4]=(short)f2b(f1.x); p0[5]=(short)f2b(f1.y); p0[6]=(short)f2b(f1.z); p0[7]=(short)f2b(f1.w);
      p1[0]=(short)f2b(f2.x); p1[1]=(short)f2b(f2.y); p1[2]=(short)f2b(f2.z); p1[3]=(short)f2b(f2.w);
      p1[4]=(short)f2b(f3.x); p1[5]=(short)f2b(f3.y); p1[6]=(short)f2b(f3.z); p1[7]=(short)f2b(f3.w);
      const int e = row*64 + scol;
      const int s8 = (row & 7) << 3;
      *(short8*)&xs[(e    ) ^ s8] = p0;
      *(short8*)&xs[(e + 8) ^ s8] = p1;
    }
    // stage WqkT tile (bf16 copy)
    #pragma unroll
    for (int rr = 0; rr < 2; ++rr) {
      const int row = srow + rr*64;
      const u16* src = WqkT + (size_t)row*C_ + k0 + scol;
      short8 q0 = *(const short8*)src;
      short8 q1 = *(const short8*)(src + 8);
      const int e = row*64 + scol;
      const int s8 = (row & 7) << 3;
      *(short8*)&bs[(e    ) ^ s8] = q0;
      *(short8*)&bs[(e + 8) ^ s8] = q1;
    }
    __syncthreads();
    #pragma unroll
    for (int ks = 0; ks < 2; ++ks) {
      const int kb = ks*32 + rg*8;
      short8 a0 = *(const short8*)&xs[((w*32      + la)*64 + kb) ^ swz];
      short8 a1 = *(const short8*)&xs[((w*32 + 16 + la)*64 + kb) ^ swz];
      #pragma unroll
      for (int ct = 0; ct < 8; ++ct) {
        short8 bb = *(const short8*)&bs[((ct*16 + la)*64 + kb) ^ swz];
        acc[0][ct] = __builtin_amdgcn_mfma_f32_16x16x32_bf16(a0, bb, acc[0][ct], 0, 0, 0);
        acc[1][ct] = __builtin_amdgcn_mfma_f32_16x16x32_bf16(a1, bb, acc[1][ct], 0, 0, 0);
      }
    }
  }

  // epilogue: bias + softmax over a (16 lanes) + attn write + gating partials
  float psum = 0.f, pmax = 0.f;
  #pragma unroll
  for (int rt = 0; rt < 2; ++rt) {
    #pragma unroll
    for (int h = 0; h < 8; ++h) {
      const float bias = bqk[h*16 + la];
      #pragma unroll
      for (int j = 0; j < 4; ++j) {
        float v = acc[rt][h][j] + bias;
        float mx = v;
        mx = fmaxf(mx, __shfl_xor(mx, 1));
        mx = fmaxf(mx, __shfl_xor(mx, 2));
        mx = fmaxf(mx, __shfl_xor(mx, 4));
        mx = fmaxf(mx, __shfl_xor(mx, 8));
        float e = __expf(v - mx);
        float s = e;
        s += __shfl_xor(s, 1); s += __shfl_xor(s, 2); s += __shfl_xor(s, 4); s += __shfl_xor(s, 8);
        float p = e * __builtin_amdgcn_rcpf(s);
        psum += p;
        pmax = fmaxf(pmax, p);
        const int row = m0 + w*32 + rt*16 + rg*4 + j;
        attn[(size_t)row*128 + h*16 + la] = f2b(p);
      }
    }
  }
  psum += __shfl_xor(psum, 16); psum += __shfl_xor(psum, 32);
  pmax = fmaxf(pmax, __shfl_xor(pmax, 16)); pmax = fmaxf(pmax, __shfl_xor(pmax, 32));
  if (lane < 16) {
    atomicAdd(&gsum[b*16 + la], psum);
    atomicMax(&gmax[b*16 + la], __float_as_uint(pmax));
  }
}

// ---------------- gate ----------------
__global__ void gate_k(const float* __restrict__ gsum, const u32* __restrict__ gmax,
                       const float* __restrict__ w1, const float* __restrict__ w2,
                       float* __restrict__ gate)
{
  int b = blockIdx.x, t = threadIdx.x;
  __shared__ float g1;
  if (t == 0) {
    float d1 = 0.f, d2 = 0.f;
    for (int a = 0; a < A_; ++a) {
      d1 += gsum[b*A_+a] * (1.0f/32768.0f) * w1[a];
      d2 += __uint_as_float(gmax[b*A_+a]) * w1[a];
    }
    g1 = fmaxf(d1, 0.f) + fmaxf(d2, 0.f);
  }
  __syncthreads();
  if (t < A_) {
    float z = g1 * w2[t];
    gate[b*A_+t] = 1.f / (1.f + __expf(-z));
  }
}

// ---------------- pass B: out GEMM ----------------
// grid 4096 (mb = bx>>2, col block = bx&3), 256 threads. M tile 128, N tile 128, K=128.
__global__ __launch_bounds__(256) void pass_b(
    const u16* __restrict__ attn, const u16* __restrict__ WvpT,
    const float* __restrict__ gate, const float* __restrict__ bp,
    float* __restrict__ out)
{
  __shared__ u16 as_[128*64];
  __shared__ u16 bs[128*64];
  __shared__ float gsh[16];
  const int t = threadIdx.x;
  const int mb = blockIdx.x >> 2, cb = blockIdx.x & 3;
  const int m0 = mb * 128, co0 = cb * 128;
  const int b = mb >> 5;
  const int w = t >> 6, lane = t & 63;
  const int la = lane & 15, rg = lane >> 4;
  const int swz = (la & 7) << 3;

  if (t < 16) gsh[t] = gate[b*16 + t];

  f32x4 acc[2][8];
  #pragma unroll
  for (int i = 0; i < 2; ++i)
    #pragma unroll
    for (int j = 0; j < 8; ++j) acc[i][j] = (f32x4){0.f,0.f,0.f,0.f};

  const int srow = t >> 2;
  const int scol = (t & 3) << 4;

  for (int kt = 0; kt < 2; ++kt) {
    const int k0 = kt * 64;
    __syncthreads();
    // stage attn tile (pure bf16 copy)
    #pragma unroll
    for (int rr = 0; rr < 2; ++rr) {
      const int row = srow + rr*64;
      const u16* src = attn + (size_t)(m0 + row)*128 + k0 + scol;
      short8 q0 = *(const short8*)src;
      short8 q1 = *(const short8*)(src + 8);
      const int e = row*64 + scol;
      const int s8 = (row & 7) << 3;
      *(short8*)&as_[(e    ) ^ s8] = q0;
      *(short8*)&as_[(e + 8) ^ s8] = q1;
    }
    // stage WvpT tile, scale row k by gate[k&15]; (k0+scol)&15 == 0 so u0 -> g[0..7], u1 -> g[8..15]
    #pragma unroll
    for (int rr = 0; rr < 2; ++rr) {
      const int row = srow + rr*64;
      const u16* src = WvpT + (size_t)(co0 + row)*128 + k0 + scol;
      short8 q0 = *(const short8*)src;
      short8 q1 = *(const short8*)(src + 8);
      short8 r0, r1;
      #pragma unroll
      for (int j = 0; j < 8; ++j) {
        r0[j] = (short)f2b(b2f((u16)q0[j]) * gsh[j]);
        r1[j] = (short)f2b(b2f((u16)q1[j]) * gsh[j + 8]);
      }
      const int e = row*64 + scol;
      const int s8 = (row & 7) << 3;
      *(short8*)&bs[(e    ) ^ s8] = r0;
      *(short8*)&bs[(e + 8) ^ s8] = r1;
    }
    __syncthreads();
    #pragma unroll
    for (int ks = 0; ks < 2; ++ks) {
      const int kb = ks*32 + rg*8;
      short8 a0 = *(const short8*)&as_[((w*32      + la)*64 + kb) ^ swz];
      short8 a1 = *(const short8*)&as_[((w*32 + 16 + la)*64 + kb) ^ swz];
      #pragma unroll
      for (int ct = 0; ct < 8; ++ct) {
        short8 bb = *(const short8*)&bs[((ct*16 + la)*64 + kb) ^ swz];
        acc[0][ct] = __builtin_amdgcn_mfma_f32_16x16x32_bf16(a0, bb, acc[0][ct], 0, 0, 0);
        acc[1][ct] = __builtin_amdgcn_mfma_f32_16x16x32_bf16(a1, bb, acc[1][ct], 0, 0, 0);
      }
    }
  }

  #pragma unroll
  for (int rt = 0; rt < 2; ++rt) {
    #pragma unroll
    for (int ct = 0; ct < 8; ++ct) {
      const int col = co0 + ct*16 + la;
      const float bias = bp[col];
      #pragma unroll
      for (int j = 0; j < 4; ++j) {
        const int row = m0 + w*32 + rt*16 + rg*4 + j;
        out[(size_t)row*C_ + col] = acc[rt][ct][j] + bias;
      }
    }
  }
}

// ---------------- launch ----------------
extern "C" void kernel_launch(void* const* d_in, const int* in_sizes, int n_in,
                              void* d_out, int out_size, void* d_ws, size_t ws_size,
                              hipStream_t stream)
{
  const float* x       = (const float*)d_in[0];
  const float* Wq      = (const float*)d_in[1];
  const float* bq      = (const float*)d_in[2];
  const float* Wk      = (const float*)d_in[3];
  const float* bk      = (const float*)d_in[4];
  const float* Wv      = (const float*)d_in[5];
  const float* bv      = (const float*)d_in[6];
  const float* Wp      = (const float*)d_in[7];
  const float* bp      = (const float*)d_in[8];
  const float* agent_k = (const float*)d_in[9];
  const float* agent_v = (const float*)d_in[10];
  const float* ca_w1   = (const float*)d_in[11];
  const float* ca_w2   = (const float*)d_in[12];
  float* out = (float*)d_out;

  char* ws = (char*)d_ws;
  u16*   attn = (u16*)(ws);                                  // 131072*128*2 = 33554432
  float* k2   = (float*)(ws + 33554432);                     // 32768
  float* v2   = (float*)(ws + 33554432 + 32768);             // 32768
  u16*   WqkT = (u16*)(ws + 33554432 + 65536);               // 131072
  float* bqk  = (float*)(ws + 33554432 + 65536 + 131072);    // 512 (pad to 2048)
  u16*   WvpT = (u16*)(ws + 33554432 + 65536 + 131072 + 2048); // 131072
  float* gsum = (float*)(ws + 33554432 + 65536 + 131072 + 2048 + 131072); // 2048
  u32*   gmax = (u32*)((char*)gsum + 2048);                  // 2048
  float* gate = (float*)((char*)gsum + 4096);                // 2048

  hipMemsetAsync(gsum, 0, 4096, stream);
  prep_kv<<<16, 256, 0, stream>>>(agent_k, Wk, bk, agent_v, Wv, bv, k2, v2);
  prep_wqk<<<512, 128, 0, stream>>>(Wq, bq, k2, WqkT, bqk);
  prep_wvp<<<128, 256, 0, stream>>>(Wp, v2, WvpT);
  pass_a<<<1024, 256, 0, stream>>>(x, WqkT, bqk, attn, gsum, gmax);
  gate_k<<<32, 64, 0, stream>>>(gsum, gmax, ca_w1, ca_w2, gate);
  pass_b<<<4096, 256, 0, stream>>>(attn, WvpT, gate, bp, out);
}